// Round 1
// baseline (5350.724 us; speedup 1.0000x reference)
//
#include <hip/hip_runtime.h>
#include <hip/hip_bf16.h>

#define N_GRAPHS 4096
#define N_ELE 16384
#define EPS 1e-5f

// ws layout in f32 words
#define A_TAB_OFF 0
#define A_CNT_OFF (A_TAB_OFF + N_GRAPHS * 64)   // 262144
#define E_TAB_OFF (A_CNT_OFF + N_GRAPHS)        // 266240
#define E_CNT_OFF (E_TAB_OFF + N_ELE * 64)      // 1314816
#define SUMS_OFF  (E_CNT_OFF + N_ELE)           // 1331200
#define SQS_OFF   (SUMS_OFF + 256)
#define SCALE_OFF (SQS_OFF + 256)
#define SHIFT_OFF (SCALE_OFF + 256)
#define WS_WORDS  (SHIFT_OFF + 256)

__device__ __forceinline__ float bf2f(unsigned s) { return __uint_as_float(s << 16); }
__device__ __forceinline__ unsigned f2bf(float f) {
  unsigned u = __float_as_uint(f);
  return (u + 0x7fffu + ((u >> 16) & 1u)) >> 16;  // RNE
}

// ---------------- K1: segment sums ----------------
__global__ void k_seg(const float* __restrict__ x, const int* __restrict__ aidx,
                      const int* __restrict__ eidx, float* __restrict__ ws, int N) {
  float* A_tab = ws + A_TAB_OFF; float* A_cnt = ws + A_CNT_OFF;
  float* E_tab = ws + E_TAB_OFF; float* E_cnt = ws + E_CNT_OFF;
  int t = threadIdx.x;
  int c = t & 63, p = (t >> 6) & 1, s = t >> 7;
  int r0 = blockIdx.x * 256;
  int rend = min(r0 + 256, N);
  if (p == 0) {
    // atom_idx is sorted: run-length accumulate in registers, flush on change
    float acc = 0.f, cnt = 0.f; int cur = -1;
    for (int r = r0 + s; r < rend; r += 2) {
      int a = aidx[r];
      float v = x[r * 128 + c];
      if (a != cur) {
        if (cur >= 0) { atomicAdd(&A_tab[cur * 64 + c], acc); if (c == 0) atomicAdd(&A_cnt[cur], cnt); }
        cur = a; acc = v; cnt = 1.f;
      } else { acc += v; cnt += 1.f; }
    }
    if (cur >= 0) { atomicAdd(&A_tab[cur * 64 + c], acc); if (c == 0) atomicAdd(&A_cnt[cur], cnt); }
  } else {
    for (int r = r0 + s; r < rend; r += 2) {
      int e = eidx[r];
      float v = x[r * 128 + 64 + c];
      atomicAdd(&E_tab[e * 64 + c], v);
      if (c == 0) atomicAdd(&E_cnt[e], 1.f);
    }
  }
}

// ---------------- K2: mean + relu ----------------
__global__ void k_fin(float* __restrict__ ws) {
  int i = blockIdx.x * blockDim.x + threadIdx.x;
  float* A_tab = ws + A_TAB_OFF; float* A_cnt = ws + A_CNT_OFF;
  float* E_tab = ws + E_TAB_OFF; float* E_cnt = ws + E_CNT_OFF;
  if (i < N_GRAPHS * 64) A_tab[i] = fmaxf(A_tab[i] / fmaxf(A_cnt[i >> 6], 1.f), 0.f);
  if (i < N_ELE * 64)    E_tab[i] = fmaxf(E_tab[i] / fmaxf(E_cnt[i >> 6], 1.f), 0.f);
}

// ---------------- K3: both 192-K GEMMs, h1/h2 -> bf16 packed into d_out ----------------
// 512 threads, 64 rows/tile. lanes=rows; wave w owns cols [w*16, w*16+16).
// z staged transposed in LDS [256][65] f32: [rdf(0:64)|bdf(64:128)|pa(128:192)|pe(192:256)].
// layer1 uses z[kw] (kw<64) / z[64+kw]; layer2 uses z[64+kw] for all kw.
// Bias rdf_b/bdf_b is skipped: per-column constants cancel exactly in batchnorm.
__global__ void k_gemm(const float* __restrict__ rdf, const float* __restrict__ bdf,
                       const int* __restrict__ aidx, const int* __restrict__ eidx,
                       const float* __restrict__ W1, const float* __restrict__ W2,
                       const float* __restrict__ ws, unsigned* __restrict__ outp, int N) {
  __shared__ float lds[16640];
  const float* A_tab = ws + A_TAB_OFF;
  const float* E_tab = ws + E_TAB_OFF;
  int t = threadIdx.x;
  int row0 = blockIdx.x * 64;
  #pragma unroll
  for (int p = 0; p < 8; ++p) {
    int e = p * 512 + t; int r = e >> 6; int c = e & 63;
    int row = row0 + r;
    float vfr = 0.f, vfb = 0.f, vpa = 0.f, vpe = 0.f;
    if (row < N) {
      vfr = rdf[row * 64 + c];
      vfb = bdf[row * 64 + c];
      vpa = A_tab[aidx[row] * 64 + c];
      vpe = E_tab[eidx[row] * 64 + c];
    }
    lds[c * 65 + r]         = vfr;
    lds[(64 + c) * 65 + r]  = vfb;
    lds[(128 + c) * 65 + r] = vpa;
    lds[(192 + c) * 65 + r] = vpe;
  }
  __syncthreads();
  int lane = t & 63, w = t >> 6, cbase = w * 16;
  float h1[16], h2[16];
  #pragma unroll
  for (int j = 0; j < 16; ++j) { h1[j] = 0.f; h2[j] = 0.f; }
  const float4* W1v = (const float4*)W1;  // [128][48]
  const float4* W2v = (const float4*)W2;
  for (int k = 0; k < 64; k += 4) {
    float z1[4], z2[4];
    #pragma unroll
    for (int i = 0; i < 4; ++i) { z1[i] = lds[(k + i) * 65 + lane]; z2[i] = lds[(64 + k + i) * 65 + lane]; }
    int kq = k >> 2;
    #pragma unroll
    for (int j = 0; j < 16; ++j) {
      float4 a = W1v[(cbase + j) * 48 + kq];
      h1[j] += z1[0]*a.x + z1[1]*a.y + z1[2]*a.z + z1[3]*a.w;
      float4 b = W2v[(cbase + j) * 48 + kq];
      h2[j] += z2[0]*b.x + z2[1]*b.y + z2[2]*b.z + z2[3]*b.w;
    }
  }
  for (int k = 64; k < 192; k += 4) {
    float zz[4];
    #pragma unroll
    for (int i = 0; i < 4; ++i) zz[i] = lds[(64 + k + i) * 65 + lane];
    int kq = k >> 2;
    #pragma unroll
    for (int j = 0; j < 16; ++j) {
      float4 a = W1v[(cbase + j) * 48 + kq];
      h1[j] += zz[0]*a.x + zz[1]*a.y + zz[2]*a.z + zz[3]*a.w;
      float4 b = W2v[(cbase + j) * 48 + kq];
      h2[j] += zz[0]*b.x + zz[1]*b.y + zz[2]*b.z + zz[3]*b.w;
    }
  }
  __syncthreads();
  // transpose h through LDS (alias) for coalesced packed-bf16 store
  unsigned* hl = (unsigned*)lds;  // [64][129] u32
  #pragma unroll
  for (int j = 0; j < 16; j += 2) {
    hl[lane * 129 + ((cbase + j) >> 1)]      = f2bf(h1[j]) | (f2bf(h1[j + 1]) << 16);
    hl[lane * 129 + 64 + ((cbase + j) >> 1)] = f2bf(h2[j]) | (f2bf(h2[j + 1]) << 16);
  }
  __syncthreads();
  #pragma unroll
  for (int p = 0; p < 16; ++p) {
    int e = p * 512 + t; int r = e >> 7; int c32 = e & 127; int row = row0 + r;
    if (row < N) outp[row * 128 + c32] = hl[r * 129 + c32];
  }
}

// ---------------- K3b: BN column sums/sumsq from packed h ----------------
__global__ void k_stats(const unsigned* __restrict__ hp, float* __restrict__ ws, int N) {
  float* sums = ws + SUMS_OFF; float* sqs = ws + SQS_OFF;
  int t = threadIdx.x;
  int c2 = t & 127, half = t >> 7;
  float s0 = 0, q0 = 0, s1 = 0, q1 = 0;
  for (int r = blockIdx.x * 2 + half; r < N; r += gridDim.x * 2) {
    unsigned u = hp[r * 128 + c2];
    float lo = bf2f(u & 0xffffu), hi = bf2f(u >> 16);
    s0 += lo; q0 += lo * lo; s1 += hi; q1 += hi * hi;
  }
  atomicAdd(&sums[2 * c2], s0);
  atomicAdd(&sums[2 * c2 + 1], s1);
  atomicAdd(&sqs[2 * c2], q0);
  atomicAdd(&sqs[2 * c2 + 1], q1);
}

// ---------------- K4: BN finalize -> scale/shift ----------------
__global__ void k_bnfin(const float* __restrict__ g1, const float* __restrict__ b1,
                        const float* __restrict__ g2, const float* __restrict__ b2,
                        float* __restrict__ ws, int N) {
  int c = threadIdx.x;  // 256
  float inv = 1.f / (float)N;
  float mu = ws[SUMS_OFF + c] * inv;
  float var = fmaxf(ws[SQS_OFF + c] * inv - mu * mu, 0.f);
  int l = c >> 7, cc = c & 127;
  float ga = l ? g2[cc] : g1[cc];
  float be = l ? b2[cc] : b1[cc];
  float sc = ga * rsqrtf(var + EPS);
  ws[SCALE_OFF + c] = sc;
  ws[SHIFT_OFF + c] = be - mu * sc;
}

// ---------------- K5: BN apply + residual + relu + fc GEMM (in-place on d_out rows) ----------------
__global__ void k_fc(const float* __restrict__ x, const float* __restrict__ Wf,
                     const float* __restrict__ bfc, const float* __restrict__ ws,
                     float* __restrict__ out, int N) {
  __shared__ float lds[16640];
  const float* scale = ws + SCALE_OFF;
  const float* shift = ws + SHIFT_OFF;
  int t = threadIdx.x;
  int row0 = blockIdx.x * 64;
  const unsigned* hp = (const unsigned*)out;
  #pragma unroll
  for (int p = 0; p < 16; ++p) {
    int e = p * 512 + t; int r = e >> 7; int c32 = e & 127; int row = row0 + r;
    float v0 = 0.f, v1 = 0.f;
    if (row < N) {
      unsigned u = hp[row * 128 + c32];
      int k0 = 2 * c32;
      float2 xv = *(const float2*)(x + row * 128 + (k0 & 127));
      v0 = fmaxf(bf2f(u & 0xffffu) * scale[k0]     + shift[k0]     + xv.x, 0.f);
      v1 = fmaxf(bf2f(u >> 16)     * scale[k0 + 1] + shift[k0 + 1] + xv.y, 0.f);
    }
    lds[(2 * c32) * 65 + r]     = v0;
    lds[(2 * c32 + 1) * 65 + r] = v1;
  }
  __syncthreads();
  int lane = t & 63, w = t >> 6, cbase = w * 16;
  float acc[16];
  #pragma unroll
  for (int j = 0; j < 16; ++j) acc[j] = bfc[cbase + j];
  const float4* Wv = (const float4*)Wf;  // [128][64]
  for (int k = 0; k < 256; k += 4) {
    float zz[4];
    #pragma unroll
    for (int i = 0; i < 4; ++i) zz[i] = lds[(k + i) * 65 + lane];
    int kq = k >> 2;
    #pragma unroll
    for (int j = 0; j < 16; ++j) {
      float4 a = Wv[(cbase + j) * 64 + kq];
      acc[j] += zz[0]*a.x + zz[1]*a.y + zz[2]*a.z + zz[3]*a.w;
    }
  }
  __syncthreads();  // done reading x12 from LDS; safe to alias
  float* ol = lds;  // [64][129] f32
  #pragma unroll
  for (int j = 0; j < 16; ++j) ol[lane * 129 + cbase + j] = fmaxf(acc[j], 0.f);
  __syncthreads();
  #pragma unroll
  for (int p = 0; p < 16; ++p) {
    int e = p * 512 + t; int r = e >> 7; int c = e & 127; int row = row0 + r;
    if (row < N) out[row * 128 + c] = ol[r * 129 + c];
  }
}

extern "C" void kernel_launch(void* const* d_in, const int* in_sizes, int n_in,
                              void* d_out, int out_size, void* d_ws, size_t ws_size,
                              hipStream_t stream) {
  const float* x    = (const float*)d_in[0];
  const float* rdf  = (const float*)d_in[1];
  const float* bdf  = (const float*)d_in[2];
  const int*   aidx = (const int*)d_in[3];
  const int*   eidx = (const int*)d_in[4];
  const float* rdfW = (const float*)d_in[5];
  // d_in[6] rdf_b: cancels in batchnorm, unused
  const float* rdfG = (const float*)d_in[7];
  const float* rdfBe= (const float*)d_in[8];
  const float* bdfW = (const float*)d_in[9];
  // d_in[10] bdf_b: cancels in batchnorm, unused
  const float* bdfG = (const float*)d_in[11];
  const float* bdfBe= (const float*)d_in[12];
  const float* fcW  = (const float*)d_in[13];
  const float* fcB  = (const float*)d_in[14];
  float* out = (float*)d_out;
  float* ws  = (float*)d_ws;
  int N = in_sizes[0] / 128;

  hipMemsetAsync(d_ws, 0, (size_t)WS_WORDS * 4, stream);
  k_seg<<<(N + 255) / 256, 256, 0, stream>>>(x, aidx, eidx, ws, N);
  k_fin<<<(N_ELE * 64 + 255) / 256, 256, 0, stream>>>(ws);
  int tiles = (N + 63) / 64;
  k_gemm<<<tiles, 512, 0, stream>>>(rdf, bdf, aidx, eidx, rdfW, bdfW, ws, (unsigned*)d_out, N);
  k_stats<<<256, 256, 0, stream>>>((const unsigned*)d_out, ws, N);
  k_bnfin<<<1, 256, 0, stream>>>(rdfG, rdfBe, bdfG, bdfBe, ws, N);
  k_fc<<<tiles, 512, 0, stream>>>(x, fcW, fcB, ws, out, N);
}

// Round 2
// 472.167 us; speedup vs baseline: 11.3323x; 11.3323x over previous
//
#include <hip/hip_runtime.h>
#include <hip/hip_bf16.h>

#define N_GRAPHS 4096
#define N_ELE 16384
#define EPS 1e-5f

// ws layout (f32 words)
#define A_TAB_OFF 0               // 4096*64 f32 atomic sums
#define A_CNT_OFF 262144          // 4096
#define E_TAB_OFF 266240          // 16384*64
#define E_CNT_OFF 1314816         // 16384
#define STAT_OFF  1331200         // 32 copies * (256 sums + 256 sqs)
#define ZERO_WORDS 1347584        // memset range: everything above
#define A_TABH_OFF 1347584        // 4096*64 bf16 = 131072 words
#define E_TABH_OFF 1478656        // 16384*64 bf16 = 524288 words
#define W1PK_OFF  2002944         // 128*192 bf16 = 12288 words (W2 right after)
#define FCPK_OFF  2027520         // 128*256 bf16 = 16384 words
#define SCALE_OFF 2043904         // 256
#define SHIFT_OFF 2044160         // 256
#define WS_WORDS  2044416         // ~8.2 MB

typedef __attribute__((ext_vector_type(8))) short bf16x8;
typedef __attribute__((ext_vector_type(4))) float f32x4;

__device__ __forceinline__ float bf2f(unsigned s) { return __uint_as_float(s << 16); }
__device__ __forceinline__ unsigned f2bf(float f) {
  unsigned u = __float_as_uint(f);
  return (u + 0x7fffu + ((u >> 16) & 1u)) >> 16;  // RNE
}

// ---------------- K0: pack W1,W2,fcW to bf16 in MFMA B-fragment order ----------------
// frag elem (ct,kb_i,lane,j): B col = ct*16 + (lane&15), k = kb*32 + (lane>>4)*8 + j
__global__ void k_prep(const float* __restrict__ W1, const float* __restrict__ W2,
                       const float* __restrict__ fcW, float* __restrict__ ws) {
  int tid = blockIdx.x * 512 + threadIdx.x;
  if (tid < 49152) {
    unsigned short* wpk = (unsigned short*)(ws + W1PK_OFF);
    int L = tid / 24576, rem = tid % 24576;
    int ct = rem / 3072, rem2 = rem % 3072;
    int i = rem2 >> 9, lane = (rem2 >> 3) & 63, j = rem2 & 7;
    int zkb = L ? (i + 2) : (i < 2 ? i : i + 2);       // z k-block visited by layer L, step i
    int zk = zkb * 32 + ((lane >> 4) << 3) + j;
    int kp = L ? (zk - 64) : (zk < 64 ? zk : zk - 64); // W's K index
    int col = ct * 16 + (lane & 15);
    const float* W = L ? W2 : W1;
    wpk[tid] = (unsigned short)f2bf(W[col * 192 + kp]);
  } else {
    int idx = tid - 49152;
    unsigned short* fpk = (unsigned short*)(ws + FCPK_OFF);
    int ct = idx >> 12, kb = (idx >> 9) & 7, lane = (idx >> 3) & 63, j = idx & 7;
    fpk[idx] = (unsigned short)f2bf(fcW[(ct * 16 + (lane & 15)) * 256 + kb * 32 + ((lane >> 4) << 3) + j]);
  }
}

// ---------------- K1: segment sums ----------------
__global__ void k_seg(const float* __restrict__ x, const int* __restrict__ aidx,
                      const int* __restrict__ eidx, float* __restrict__ ws, int N) {
  float* A_tab = ws + A_TAB_OFF; float* A_cnt = ws + A_CNT_OFF;
  float* E_tab = ws + E_TAB_OFF; float* E_cnt = ws + E_CNT_OFF;
  int t = threadIdx.x;
  int c = t & 63, p = (t >> 6) & 1, s = t >> 7;
  int r0 = blockIdx.x * 256;
  int rend = min(r0 + 256, N);
  if (p == 0) {
    float acc = 0.f, cnt = 0.f; int cur = -1;
    for (int r = r0 + s; r < rend; r += 2) {
      int a = aidx[r];
      float v = x[(size_t)r * 128 + c];
      if (a != cur) {
        if (cur >= 0) { atomicAdd(&A_tab[cur * 64 + c], acc); if (c == 0) atomicAdd(&A_cnt[cur], cnt); }
        cur = a; acc = v; cnt = 1.f;
      } else { acc += v; cnt += 1.f; }
    }
    if (cur >= 0) { atomicAdd(&A_tab[cur * 64 + c], acc); if (c == 0) atomicAdd(&A_cnt[cur], cnt); }
  } else {
    for (int r = r0 + s; r < rend; r += 2) {
      int e = eidx[r];
      float v = x[(size_t)r * 128 + 64 + c];
      atomicAdd(&E_tab[e * 64 + c], v);
      if (c == 0) atomicAdd(&E_cnt[e], 1.f);
    }
  }
}

// ---------------- K2: mean + relu -> bf16 tables ----------------
__global__ void k_fin(float* __restrict__ ws) {
  int i = blockIdx.x * 256 + threadIdx.x;
  unsigned* w32 = (unsigned*)ws;
  if (i < 131072) {
    int e = 2 * i;
    float cnt = fmaxf(ws[A_CNT_OFF + (e >> 6)], 1.f);
    float v0 = fmaxf(ws[A_TAB_OFF + e] / cnt, 0.f);
    float v1 = fmaxf(ws[A_TAB_OFF + e + 1] / cnt, 0.f);
    w32[A_TABH_OFF + i] = f2bf(v0) | (f2bf(v1) << 16);
  }
  if (i < 524288) {
    int e = 2 * i;
    float cnt = fmaxf(ws[E_CNT_OFF + (e >> 6)], 1.f);
    float v0 = fmaxf(ws[E_TAB_OFF + e] / cnt, 0.f);
    float v1 = fmaxf(ws[E_TAB_OFF + e + 1] / cnt, 0.f);
    w32[E_TABH_OFF + i] = f2bf(v0) | (f2bf(v1) << 16);
  }
}

// ---------------- K3: MFMA dual GEMM (K=192 x2), h -> bf16 packed in d_out, fused BN stats ----------------
// 512 thr, 64 rows/block. z LDS [64 rows][256 k] bf16, XOR-swizzled byte ^= (row&7)<<4.
// wave w: layer L=w>>2, col-group ctp=w&3 (32 cols). Bias cancels in BN (skipped).
__global__ __launch_bounds__(512) void k_gemm(
    const float* __restrict__ rdf, const float* __restrict__ bdf,
    const int* __restrict__ aidx, const int* __restrict__ eidx,
    float* __restrict__ ws, unsigned* __restrict__ outp, int N) {
  __shared__ __align__(16) char smem[33792];
  const unsigned short* Atabh = (const unsigned short*)(ws + A_TABH_OFF);
  const unsigned short* Etabh = (const unsigned short*)(ws + E_TABH_OFF);
  int t = threadIdx.x;
  int row0 = blockIdx.x * 64;
  // ---- stage z ----
  {
    int r = t >> 3, g = t & 7;             // row, 32-col group (zc0 = g*32)
    int row = row0 + r;
    unsigned wv[16];
    if (row < N) {
      if (g < 4) {
        const float* src = ((g < 2) ? rdf : bdf) + (size_t)row * 64 + (g & 1) * 32;
        #pragma unroll
        for (int i = 0; i < 8; ++i) {
          float4 f = ((const float4*)src)[i];
          wv[i * 2]     = f2bf(f.x) | (f2bf(f.y) << 16);
          wv[i * 2 + 1] = f2bf(f.z) | (f2bf(f.w) << 16);
        }
      } else {
        const unsigned short* tab = (g < 6) ? Atabh : Etabh;
        int idx = (g < 6) ? aidx[row] : eidx[row];
        const uint4* srcv = (const uint4*)(tab + (size_t)idx * 64 + (g & 1) * 32);
        #pragma unroll
        for (int i = 0; i < 4; ++i) ((uint4*)wv)[i] = srcv[i];
      }
    } else {
      #pragma unroll
      for (int i = 0; i < 16; ++i) wv[i] = 0u;
    }
    int zc0 = g * 32;
    #pragma unroll
    for (int i = 0; i < 4; ++i) {
      int byte = r * 512 + (((zc0 + i * 8) * 2) ^ ((r & 7) << 4));
      *(uint4*)(smem + byte) = ((uint4*)wv)[i];
    }
  }
  __syncthreads();
  // ---- MFMA ----
  int l = t & 63, w = t >> 6;
  int L = w >> 2, ctp = w & 3;
  f32x4 acc[4][2];
  #pragma unroll
  for (int mt = 0; mt < 4; ++mt)
    #pragma unroll
    for (int cti = 0; cti < 2; ++cti) acc[mt][cti] = (f32x4){0.f, 0.f, 0.f, 0.f};
  const unsigned short* Wpk = (const unsigned short*)(ws + W1PK_OFF) + L * 24576;
  #pragma unroll
  for (int i = 0; i < 6; ++i) {
    int zkb = L ? (i + 2) : (i < 2 ? i : i + 2);
    bf16x8 af[4];
    #pragma unroll
    for (int mt = 0; mt < 4; ++mt) {
      int rr = mt * 16 + (l & 15);
      int byte = rr * 512 + ((zkb * 64 + ((l >> 4) << 4)) ^ ((rr & 7) << 4));
      af[mt] = *(const bf16x8*)(smem + byte);
    }
    #pragma unroll
    for (int cti = 0; cti < 2; ++cti) {
      int ct = ctp * 2 + cti;
      bf16x8 bfr = *(const bf16x8*)(Wpk + ((ct * 6 + i) * 64 + l) * 8);
      #pragma unroll
      for (int mt = 0; mt < 4; ++mt)
        acc[mt][cti] = __builtin_amdgcn_mfma_f32_16x16x32_bf16(af[mt], bfr, acc[mt][cti], 0, 0, 0);
    }
  }
  // ---- fused BN stats: per-wave col partials -> shfl reduce -> 32-copy atomics ----
  float ssum[2], ssq[2];
  #pragma unroll
  for (int cti = 0; cti < 2; ++cti) {
    float s = 0.f, q = 0.f;
    #pragma unroll
    for (int mt = 0; mt < 4; ++mt)
      #pragma unroll
      for (int rr = 0; rr < 4; ++rr) { float v = acc[mt][cti][rr]; s += v; q += v * v; }
    s += __shfl_xor(s, 16); s += __shfl_xor(s, 32);
    q += __shfl_xor(q, 16); q += __shfl_xor(q, 32);
    ssum[cti] = s; ssq[cti] = q;
  }
  {
    float* stat = ws + STAT_OFF + (blockIdx.x & 31) * 512;
    if (l < 16) {
      #pragma unroll
      for (int cti = 0; cti < 2; ++cti) {
        int gc = L * 128 + ctp * 32 + cti * 16 + l;
        atomicAdd(&stat[gc], ssum[cti]);
        atomicAdd(&stat[256 + gc], ssq[cti]);
      }
    }
  }
  // ---- epilogue: pack bf16 pairs via lane^1 shfl, LDS transpose, coalesced store ----
  __syncthreads();
  unsigned* hl = (unsigned*)smem;  // [64][132]
  #pragma unroll
  for (int mt = 0; mt < 4; ++mt)
    #pragma unroll
    for (int cti = 0; cti < 2; ++cti)
      #pragma unroll
      for (int rr = 0; rr < 4; ++rr) {
        unsigned ub = f2bf(acc[mt][cti][rr]);
        unsigned pb = (unsigned)__shfl_xor((int)ub, 1);
        if (!(l & 1)) {
          int orow = mt * 16 + ((l >> 4) << 2) + rr;
          int colp = (L * 128 + ctp * 32 + cti * 16 + (l & 15)) >> 1;
          hl[orow * 132 + colp] = ub | (pb << 16);
        }
      }
  __syncthreads();
  #pragma unroll
  for (int p = 0; p < 4; ++p) {
    int e = p * 512 + t;
    int rr = e >> 5, v4 = e & 31;
    if (row0 + rr < N)
      ((uint4*)outp)[(size_t)(row0 + rr) * 32 + v4] = *(uint4*)&hl[rr * 132 + v4 * 4];
  }
}

// ---------------- K4: BN finalize -> scale/shift ----------------
__global__ void k_bnfin(const float* __restrict__ g1, const float* __restrict__ b1,
                        const float* __restrict__ g2, const float* __restrict__ b2,
                        float* __restrict__ ws, int N) {
  int c = threadIdx.x;  // 256
  float s = 0.f, q = 0.f;
  for (int m = 0; m < 32; ++m) { s += ws[STAT_OFF + m * 512 + c]; q += ws[STAT_OFF + m * 512 + 256 + c]; }
  float inv = 1.f / (float)N;
  float mu = s * inv;
  float var = fmaxf(q * inv - mu * mu, 0.f);
  int lyr = c >> 7, cc = c & 127;
  float ga = lyr ? g2[cc] : g1[cc];
  float be = lyr ? b2[cc] : b1[cc];
  float sc = ga * rsqrtf(var + EPS);
  ws[SCALE_OFF + c] = sc;
  ws[SHIFT_OFF + c] = be - mu * sc;
}

// ---------------- K5: BN apply + residual + relu + MFMA fc GEMM (in-place on d_out) ----------------
__global__ __launch_bounds__(512) void k_fc(
    const float* __restrict__ x, const float* __restrict__ fcb,
    float* __restrict__ ws, float* __restrict__ out, int N) {
  __shared__ __align__(16) char smem[33792];
  __shared__ float scsh[512];
  int t = threadIdx.x;
  int row0 = blockIdx.x * 64;
  scsh[t] = ws[SCALE_OFF + t];  // SCALE(256) then SHIFT(256) contiguous
  const unsigned* hp = (const unsigned*)out;
  // ---- stage: load h + x ----
  int r = t >> 3, g = t & 7;
  int row = row0 + r;
  unsigned hw[16]; float xr[32];
  if (row < N) {
    #pragma unroll
    for (int i = 0; i < 4; ++i) ((uint4*)hw)[i] = ((const uint4*)(hp + (size_t)row * 128 + g * 16))[i];
    #pragma unroll
    for (int i = 0; i < 8; ++i) ((float4*)xr)[i] = ((const float4*)(x + (size_t)row * 128 + (g & 3) * 32))[i];
  } else {
    #pragma unroll
    for (int i = 0; i < 16; ++i) hw[i] = 0u;
    #pragma unroll
    for (int i = 0; i < 32; ++i) xr[i] = 0.f;
  }
  __syncthreads();  // scsh ready
  {
    unsigned outw[16];
    if (row < N) {
      #pragma unroll
      for (int j = 0; j < 16; ++j) {
        int c = g * 32 + 2 * j;
        float lo = bf2f(hw[j] & 0xffffu) * scsh[c] + scsh[256 + c] + xr[2 * j];
        float hi = bf2f(hw[j] >> 16) * scsh[c + 1] + scsh[256 + c + 1] + xr[2 * j + 1];
        outw[j] = f2bf(fmaxf(lo, 0.f)) | (f2bf(fmaxf(hi, 0.f)) << 16);
      }
    } else {
      #pragma unroll
      for (int j = 0; j < 16; ++j) outw[j] = 0u;
    }
    #pragma unroll
    for (int i = 0; i < 4; ++i) {
      int byte = r * 512 + (((g * 32 + i * 8) * 2) ^ ((r & 7) << 4));
      *(uint4*)(smem + byte) = ((uint4*)outw)[i];
    }
  }
  __syncthreads();
  // ---- MFMA K=256: wave w -> col-tile w ----
  int l = t & 63, w = t >> 6;
  f32x4 acc[4];
  #pragma unroll
  for (int mt = 0; mt < 4; ++mt) acc[mt] = (f32x4){0.f, 0.f, 0.f, 0.f};
  const unsigned short* Fpk = (const unsigned short*)(ws + FCPK_OFF);
  #pragma unroll
  for (int kb = 0; kb < 8; ++kb) {
    bf16x8 bfr = *(const bf16x8*)(Fpk + ((w * 8 + kb) * 64 + l) * 8);
    #pragma unroll
    for (int mt = 0; mt < 4; ++mt) {
      int rr = mt * 16 + (l & 15);
      int byte = rr * 512 + ((kb * 64 + ((l >> 4) << 4)) ^ ((rr & 7) << 4));
      bf16x8 af = *(const bf16x8*)(smem + byte);
      acc[mt] = __builtin_amdgcn_mfma_f32_16x16x32_bf16(af, bfr, acc[mt], 0, 0, 0);
    }
  }
  float bias = fcb[(w << 4) + (l & 15)];
  __syncthreads();
  float* ol = (float*)smem;  // [64][132]
  #pragma unroll
  for (int mt = 0; mt < 4; ++mt)
    #pragma unroll
    for (int rr = 0; rr < 4; ++rr)
      ol[(mt * 16 + ((l >> 4) << 2) + rr) * 132 + (w << 4) + (l & 15)] = fmaxf(acc[mt][rr] + bias, 0.f);
  __syncthreads();
  #pragma unroll
  for (int p = 0; p < 4; ++p) {
    int e = p * 512 + t;
    int rr = e >> 5, v4 = e & 31;
    if (row0 + rr < N)
      ((float4*)out)[(size_t)(row0 + rr) * 32 + v4] = *(float4*)&ol[rr * 132 + v4 * 4];
  }
}

extern "C" void kernel_launch(void* const* d_in, const int* in_sizes, int n_in,
                              void* d_out, int out_size, void* d_ws, size_t ws_size,
                              hipStream_t stream) {
  const float* x    = (const float*)d_in[0];
  const float* rdf  = (const float*)d_in[1];
  const float* bdf  = (const float*)d_in[2];
  const int*   aidx = (const int*)d_in[3];
  const int*   eidx = (const int*)d_in[4];
  const float* rdfW = (const float*)d_in[5];
  const float* rdfG = (const float*)d_in[7];
  const float* rdfBe= (const float*)d_in[8];
  const float* bdfW = (const float*)d_in[9];
  const float* bdfG = (const float*)d_in[11];
  const float* bdfBe= (const float*)d_in[12];
  const float* fcW  = (const float*)d_in[13];
  const float* fcB  = (const float*)d_in[14];
  float* out = (float*)d_out;
  float* ws  = (float*)d_ws;
  int N = in_sizes[0] / 128;

  hipMemsetAsync(d_ws, 0, (size_t)ZERO_WORDS * 4, stream);
  k_prep<<<160, 512, 0, stream>>>(rdfW, bdfW, fcW, ws);
  k_seg<<<(N + 255) / 256, 256, 0, stream>>>(x, aidx, eidx, ws, N);
  k_fin<<<2048, 256, 0, stream>>>(ws);
  int tiles = (N + 63) / 64;
  k_gemm<<<tiles, 512, 0, stream>>>(rdf, bdf, aidx, eidx, ws, (unsigned*)d_out, N);
  k_bnfin<<<1, 256, 0, stream>>>(rdfG, rdfBe, bdfG, bdfBe, ws, N);
  k_fc<<<tiles, 512, 0, stream>>>(x, fcB, ws, out, N);
}